// Round 6
// baseline (334.453 us; speedup 1.0000x reference)
//
#include <hip/hip_runtime.h>

#define NNODES 100000
#define NEDGES 1600000
#define BSHIFT 7
#define NB 782            // buckets of 128 nodes: bucket = dst >> 7
#define CAP 2560          // padded per-bucket capacity (mean 2048, +11 sigma)
#define EBLOCKS 391       // edge-scatter blocks (4096 edges each)
#define GEMM_BLOCKS 1563  // (NNODES + 63) / 64

typedef _Float16 f16;
typedef _Float16 v8h __attribute__((ext_vector_type(8)));
typedef float v4f __attribute__((ext_vector_type(4)));

// Single-instruction byte->float decode (v_cvt_f32_ubyteN), with safe fallback.
#if __has_builtin(__builtin_amdgcn_cvt_f32_ubyte0)
#define CVTB0(u) __builtin_amdgcn_cvt_f32_ubyte0(u)
#define CVTB1(u) __builtin_amdgcn_cvt_f32_ubyte1(u)
#define CVTB2(u) __builtin_amdgcn_cvt_f32_ubyte2(u)
#define CVTB3(u) __builtin_amdgcn_cvt_f32_ubyte3(u)
#else
#define CVTB0(u) ((float)((u) & 0xFFu))
#define CVTB1(u) ((float)(((u) >> 8) & 0xFFu))
#define CVTB2(u) ((float)(((u) >> 16) & 0xFFu))
#define CVTB3(u) ((float)((u) >> 24))
#endif

__device__ inline void accw(float s, unsigned u, float* a) {
    a[0] = fmaf(s, CVTB0(u), a[0]);
    a[1] = fmaf(s, CVTB1(u), a[1]);
    a[2] = fmaf(s, CVTB2(u), a[2]);
    a[3] = fmaf(s, CVTB3(u), a[3]);
}
__device__ inline void acc16(float s, uint4 u, float* a) {
    accw(s, u.x, a);
    accw(s, u.y, a + 4);
    accw(s, u.z, a + 8);
    accw(s, u.w, a + 12);
}

// ---------------------------------------------------------------------------
// Init: bucket cursors (bcur[b] = b*CAP) + weight transpose/convert to f16.
// ---------------------------------------------------------------------------
__global__ __launch_bounds__(256) void init_k(int* __restrict__ bcur,
                                              const float* __restrict__ W1,
                                              f16* __restrict__ W1t,
                                              const float* __restrict__ W2,
                                              f16* __restrict__ W2t) {
    int t = blockIdx.x * 256 + threadIdx.x;
    if (t < NB) bcur[t] = t * CAP;
    int u = t - 1024;
    if (u >= 0) {
        if (u < 128 * 128) {
            int k = u >> 7, n = u & 127;
            W1t[n * 128 + k] = (f16)W1[k * 128 + n];
        } else if (u < 128 * 128 + 128 * 64) {
            int v = u - 128 * 128;
            int k = v >> 6, n = v & 63;
            W2t[n * 128 + k] = (f16)W2[k * 64 + n];
        }
    }
}

// ---------------------------------------------------------------------------
// Fused: edge scatter into bucket-padded ebuf (blocks 0..EBLOCKS-1) +
// layer-1 MFMA GEMM (remaining blocks). z1 stored as per-row-scaled int8
// (biased uint8, 128 B rows) + sc1[node] = rowmax/127.
// ebuf entry packed 4B: src | (dst&127)<<24  (src < 2^17).
// ---------------------------------------------------------------------------
__global__ __launch_bounds__(256) void scatter_gemm1(
    const int* __restrict__ src, const int* __restrict__ dst,
    int* __restrict__ bcur, int* __restrict__ ebuf,
    const float* __restrict__ feat, const f16* __restrict__ W1t,
    unsigned char* __restrict__ z1, float* __restrict__ sc1) {
    constexpr int PITCH = 136;
    __shared__ __align__(16) char smem[128 * PITCH * 2];  // 34816 B
    int tid = threadIdx.x;

    if (blockIdx.x < EBLOCKS) {
        int* h = (int*)smem;
        int* base_s = ((int*)smem) + 1024;
        for (int i = tid; i < NB; i += 256) h[i] = 0;
        __syncthreads();
        int base = blockIdx.x * 4096;
        int d[16], sv[16];
        for (int k = 0; k < 16; k++) {
            int e = base + k * 256 + tid;
            if (e < NEDGES) {
                d[k] = dst[e];
                sv[k] = src[e];
                atomicAdd(&h[d[k] >> BSHIFT], 1);
            } else {
                d[k] = -1;
            }
        }
        __syncthreads();
        for (int i = tid; i < NB; i += 256) {
            int c = h[i];
            if (c) base_s[i] = atomicAdd(&bcur[i], c);
            h[i] = 0;
        }
        __syncthreads();
        for (int k = 0; k < 16; k++) {
            if (d[k] >= 0) {
                int b = d[k] >> BSHIFT;
                int slot = atomicAdd(&h[b], 1);
                ebuf[base_s[b] + slot] = sv[k] | ((d[k] & 127) << 24);
            }
        }
        return;
    }

    // ---- GEMM-1 branch: z1 = int8(f16(feat) @ W1t^T), per-row scale ----
    f16* wlds = (f16*)smem;
    for (int c = tid; c < 128 * 16; c += 256) {
        int n = c >> 4;
        int kc = c & 15;
        *(v8h*)&wlds[n * PITCH + kc * 8] = *(const v8h*)&W1t[n * 128 + kc * 8];
    }
    __syncthreads();

    int wave = tid >> 6, lane = tid & 63, quad = lane >> 4, l16 = lane & 15;
    int m0 = (blockIdx.x - EBLOCKS) * 64 + wave * 16;
    if (m0 >= NNODES) return;  // NNODES % 16 == 0

    v8h a[4];
    const float* arow = feat + (long)(m0 + l16) * 128 + quad * 8;
#pragma unroll
    for (int kb = 0; kb < 4; kb++) {
        float4 f0 = *(const float4*)(arow + kb * 32);
        float4 f1 = *(const float4*)(arow + kb * 32 + 4);
        v8h t = {(f16)f0.x, (f16)f0.y, (f16)f0.z, (f16)f0.w,
                 (f16)f1.x, (f16)f1.y, (f16)f1.z, (f16)f1.w};
        a[kb] = t;
    }

    v4f acc[8];
#pragma unroll
    for (int nt = 0; nt < 8; nt++) {
        v4f c4 = {0.f, 0.f, 0.f, 0.f};
        const f16* brow = &wlds[(nt * 16 + l16) * PITCH + quad * 8];
#pragma unroll
        for (int kb = 0; kb < 4; kb++) {
            v8h b = *(const v8h*)(brow + kb * 32);
            c4 = __builtin_amdgcn_mfma_f32_16x16x32_f16(a[kb], b, c4, 0, 0, 0);
        }
        acc[nt] = c4;
    }

    // per-row (quad,r) max over 8 nt (lane) x 16 l16 lanes, then int8 encode
#pragma unroll
    for (int r = 0; r < 4; r++) {
        float m = 0.f;
#pragma unroll
        for (int nt = 0; nt < 8; nt++) m = fmaxf(m, fabsf(acc[nt][r]));
        m = fmaxf(m, __shfl_xor(m, 1));
        m = fmaxf(m, __shfl_xor(m, 2));
        m = fmaxf(m, __shfl_xor(m, 4));
        m = fmaxf(m, __shfl_xor(m, 8));
        int row = m0 + quad * 4 + r;
        float rs = (m > 0.f) ? 127.f / m : 0.f;
        if (l16 == 0) sc1[row] = (m > 0.f) ? m / 127.f : 0.f;
#pragma unroll
        for (int nt = 0; nt < 8; nt++) {
            int qv = (int)rintf(acc[nt][r] * rs) + 128;
            z1[(long)row * 128 + nt * 16 + l16] = (unsigned char)qv;
        }
    }
}

// ---------------------------------------------------------------------------
// Per-bucket CSR fill (padded layout). Emits TWO edge arrays:
//   csr4[pos] = src                  (for gather64)
//   csr8[pos] = {src, f32 sc1[src]} (for gather128 -- kills the dependent
//                                    per-edge scale load there)
// ---------------------------------------------------------------------------
__global__ __launch_bounds__(256) void fill_bucket(const int* __restrict__ ebuf,
                                                   const int* __restrict__ bcur,
                                                   const float* __restrict__ sc1,
                                                   int* __restrict__ begs,
                                                   int* __restrict__ ends,
                                                   int* __restrict__ csr4,
                                                   int2* __restrict__ csr8) {
    __shared__ int lc[128];
    __shared__ int ls[256];
    int b = blockIdx.x;
    int tid = threadIdx.x;
    if (tid < 128) lc[tid] = 0;
    __syncthreads();
    int ebeg = b * CAP;
    int eend = bcur[b];  // = b*CAP + bucket count
    for (int e = ebeg + tid; e < eend; e += 256)
        atomicAdd(&lc[((unsigned)ebuf[e]) >> 24], 1);
    __syncthreads();
    int cnt = (tid < 128) ? lc[tid] : 0;
    ls[tid] = cnt;
    __syncthreads();
    for (int off = 1; off < 256; off <<= 1) {
        int t = (tid >= off) ? ls[tid - off] : 0;
        __syncthreads();
        ls[tid] += t;
        __syncthreads();
    }
    int excl = ls[tid] - cnt;
    int node = (b << BSHIFT) + tid;
    if (tid < 128 && node < NNODES) {
        begs[node] = ebeg + excl;
        ends[node] = ebeg + excl + cnt;
    }
    if (tid < 128) { ls[tid] = excl; lc[tid] = 0; }
    __syncthreads();
    for (int e = ebeg + tid; e < eend; e += 256) {
        int p = ebuf[e];
        int dloc = ((unsigned)p) >> 24;
        int s = p & 0xFFFFFF;
        int slot = atomicAdd(&lc[dloc], 1);
        int pos = ebeg + ls[dloc] + slot;
        csr4[pos] = s;
        csr8[pos] = make_int2(s, __float_as_int(sc1[s]));
    }
}

// ---------------------------------------------------------------------------
// Fused layer-1 gather + layer-2 projection. 1024-thread blocks = 16 waves;
// wave = 8x 8-LANE subgroups (one node each, 8 nodes/wave -> 128 nodes/block).
// Lane owns 16 channels (uint4 = 16B of the 128B int8 row). csr8 supplies
// {index, scale} in one 8B load. Decode = v_cvt_f32_ubyteN + fma; bias
// identity sum = SUM s_i*(q_i+128) - 128*SUM s_i. h1 -> f16 atile[128] ->
// 32-tile (8x4) MFMA epilogue over all 16 waves -> z2 int8 + sc2.
// ---------------------------------------------------------------------------
__global__ __launch_bounds__(1024, 8) void gather128_gemm2(
    const unsigned char* __restrict__ z,  // z1, 128 B int8 rows
    const float* __restrict__ sc,         // sc1[NNODES] (self term)
    const int2* __restrict__ csr8,        // {src, f32 scale}
    const int* __restrict__ begs, const int* __restrict__ ends,
    const float* __restrict__ b1,     // [128]
    const f16* __restrict__ W2t,      // [64,128]
    unsigned char* __restrict__ z2,   // [NNODES,64] int8
    float* __restrict__ sc2)          // sc2[NNODES]
{
    constexpr int PITCH = 136;
    __shared__ f16 w2lds[64 * PITCH];    // 17408 B
    __shared__ f16 atile[128 * PITCH];   // 34816 B
    __shared__ int rmax[128];
    int tid = threadIdx.x;

    // stage W2t (1024 threads, exactly 64*16 8-half chunks)
    {
        int n = tid >> 4, kc = tid & 15;
        *(v8h*)&w2lds[n * PITCH + kc * 8] = *(const v8h*)&W2t[n * 128 + kc * 8];
    }
    if (tid < 128) rmax[tid] = 0;

    int wavei = tid >> 6;   // wave 0..15
    int lane = tid & 63;
    int sub = lane >> 3;    // subgroup 0..7 (one node each)
    int c = lane & 7;       // channel block: c*16 .. c*16+15
    int lnode = wavei * 8 + sub;             // 0..127
    int node = blockIdx.x * 128 + lnode;     // 782*128 = 100096 >= NNODES

    int beg = 0, end = 0;
    if (node < NNODES) { beg = begs[node]; end = ends[node]; }

    unsigned coff = (unsigned)c << 4;   // byte offset of this lane's 16B chunk

    float a[16];
#pragma unroll
    for (int j = 0; j < 16; j++) a[j] = 0.f;
    float ssum = 0.f;

    // self row
    if (node < NNODES) {
        float s = sc[node];
        uint4 u = *(const uint4*)(z + (((unsigned)node) << 7) + coff);
        ssum += s;
        acc16(s, u, a);
    }

    int e = beg;
    while (__any(e < end)) {
        int2 q0 = {0, 0}, q1 = {0, 0}, q2 = {0, 0}, q3 = {0, 0};
        int2 q4 = {0, 0}, q5 = {0, 0}, q6 = {0, 0}, q7 = {0, 0};
        if (e     < end) q0 = csr8[e];
        if (e + 1 < end) q1 = csr8[e + 1];
        if (e + 2 < end) q2 = csr8[e + 2];
        if (e + 3 < end) q3 = csr8[e + 3];
        if (e + 4 < end) q4 = csr8[e + 4];
        if (e + 5 < end) q5 = csr8[e + 5];
        if (e + 6 < end) q6 = csr8[e + 6];
        if (e + 7 < end) q7 = csr8[e + 7];
        uint4 r0 = {0,0,0,0}, r1 = {0,0,0,0}, r2 = {0,0,0,0}, r3 = {0,0,0,0};
        uint4 r4 = {0,0,0,0}, r5 = {0,0,0,0}, r6 = {0,0,0,0}, r7 = {0,0,0,0};
        if (e     < end) r0 = *(const uint4*)(z + (((unsigned)q0.x) << 7) + coff);
        if (e + 1 < end) r1 = *(const uint4*)(z + (((unsigned)q1.x) << 7) + coff);
        if (e + 2 < end) r2 = *(const uint4*)(z + (((unsigned)q2.x) << 7) + coff);
        if (e + 3 < end) r3 = *(const uint4*)(z + (((unsigned)q3.x) << 7) + coff);
        if (e + 4 < end) r4 = *(const uint4*)(z + (((unsigned)q4.x) << 7) + coff);
        if (e + 5 < end) r5 = *(const uint4*)(z + (((unsigned)q5.x) << 7) + coff);
        if (e + 6 < end) r6 = *(const uint4*)(z + (((unsigned)q6.x) << 7) + coff);
        if (e + 7 < end) r7 = *(const uint4*)(z + (((unsigned)q7.x) << 7) + coff);
        float s0 = __int_as_float(q0.y), s1 = __int_as_float(q1.y);
        float s2 = __int_as_float(q2.y), s3 = __int_as_float(q3.y);
        float s4 = __int_as_float(q4.y), s5 = __int_as_float(q5.y);
        float s6 = __int_as_float(q6.y), s7 = __int_as_float(q7.y);
        ssum += ((s0 + s1) + (s2 + s3)) + ((s4 + s5) + (s6 + s7));
        acc16(s0, r0, a); acc16(s1, r1, a); acc16(s2, r2, a); acc16(s3, r3, a);
        acc16(s4, r4, a); acc16(s5, r5, a); acc16(s6, r6, a); acc16(s7, r7, a);
        e += 8;
    }

    // normalize + bias + relu -> atile (no cross-lane reduce needed)
    {
        float base = 128.f * ssum;
        float inv = 1.0f / (float)(end - beg + 1);
        float4 bb0 = ((const float4*)b1)[c * 4];
        float4 bb1 = ((const float4*)b1)[c * 4 + 1];
        float4 bb2 = ((const float4*)b1)[c * 4 + 2];
        float4 bb3 = ((const float4*)b1)[c * 4 + 3];
        v8h o0 = {(f16)fmaxf((a[0] - base) * inv + bb0.x, 0.f),
                  (f16)fmaxf((a[1] - base) * inv + bb0.y, 0.f),
                  (f16)fmaxf((a[2] - base) * inv + bb0.z, 0.f),
                  (f16)fmaxf((a[3] - base) * inv + bb0.w, 0.f),
                  (f16)fmaxf((a[4] - base) * inv + bb1.x, 0.f),
                  (f16)fmaxf((a[5] - base) * inv + bb1.y, 0.f),
                  (f16)fmaxf((a[6] - base) * inv + bb1.z, 0.f),
                  (f16)fmaxf((a[7] - base) * inv + bb1.w, 0.f)};
        v8h o1 = {(f16)fmaxf((a[8] - base) * inv + bb2.x, 0.f),
                  (f16)fmaxf((a[9] - base) * inv + bb2.y, 0.f),
                  (f16)fmaxf((a[10] - base) * inv + bb2.z, 0.f),
                  (f16)fmaxf((a[11] - base) * inv + bb2.w, 0.f),
                  (f16)fmaxf((a[12] - base) * inv + bb3.x, 0.f),
                  (f16)fmaxf((a[13] - base) * inv + bb3.y, 0.f),
                  (f16)fmaxf((a[14] - base) * inv + bb3.z, 0.f),
                  (f16)fmaxf((a[15] - base) * inv + bb3.w, 0.f)};
        *(v8h*)&atile[lnode * PITCH + c * 16] = o0;
        *(v8h*)&atile[lnode * PITCH + c * 16 + 8] = o1;
    }
    __syncthreads();

    // ---- epilogue: z2[128 rows] = int8(atile @ W2t^T); 32 tiles (8x4),
    //      wave w handles tiles w and w+16.
    int quad = lane >> 4, l16 = lane & 15;
    v4f acc2[2];
#pragma unroll
    for (int ti = 0; ti < 2; ti++) {
        int t = wavei + ti * 16;
        int wr = t >> 2, wc = t & 3;
        const f16* arow = &atile[(wr * 16 + l16) * PITCH + quad * 8];
        const f16* brow = &w2lds[(wc * 16 + l16) * PITCH + quad * 8];
        v4f acc = {0.f, 0.f, 0.f, 0.f};
#pragma unroll
        for (int kb = 0; kb < 4; kb++) {
            v8h av = *(const v8h*)(arow + kb * 32);
            v8h bv = *(const v8h*)(brow + kb * 32);
            acc = __builtin_amdgcn_mfma_f32_16x16x32_f16(av, bv, acc, 0, 0, 0);
        }
        acc2[ti] = acc;
        // per-row |max| across 16 l16 lanes, then across the 4 wc waves
#pragma unroll
        for (int r = 0; r < 4; r++) {
            float m = fabsf(acc[r]);
            m = fmaxf(m, __shfl_xor(m, 1));
            m = fmaxf(m, __shfl_xor(m, 2));
            m = fmaxf(m, __shfl_xor(m, 4));
            m = fmaxf(m, __shfl_xor(m, 8));
            if (l16 == 0) atomicMax(&rmax[wr * 16 + quad * 4 + r], __float_as_int(m));
        }
    }
    __syncthreads();
#pragma unroll
    for (int ti = 0; ti < 2; ti++) {
        int t = wavei + ti * 16;
        int wr = t >> 2, wc = t & 3;
#pragma unroll
        for (int r = 0; r < 4; r++) {
            int lrow = wr * 16 + quad * 4 + r;
            int row = blockIdx.x * 128 + lrow;
            if (row < NNODES) {
                float m = __int_as_float(rmax[lrow]);
                float rs = (m > 0.f) ? 127.f / m : 0.f;
                int qv = (int)rintf(acc2[ti][r] * rs) + 128;
                z2[(long)row * 64 + wc * 16 + l16] = (unsigned char)qv;
                if (l16 == 0 && wc == 0) sc2[row] = (m > 0.f) ? m / 127.f : 0.f;
            }
        }
    }
}

// ---------------------------------------------------------------------------
// Layer-2 gather+normalize, 4-LANE subgroups (16 nodes/wave): lane owns 16
// channels (uint4 = 16B of the 64B int8 z2 row). Same decode + bias identity.
// ---------------------------------------------------------------------------
__global__ __launch_bounds__(256, 8) void gather64(
    const unsigned char* __restrict__ z, const float* __restrict__ sc,
    const int* __restrict__ begs, const int* __restrict__ ends,
    const int* __restrict__ csr,
    const float* __restrict__ bias, float4* __restrict__ out) {
    int tid = threadIdx.x;
    int node = blockIdx.x * 64 + (tid >> 2);  // 1563*64 = 100032 >= NNODES
    if (node >= NNODES) return;
    int c = tid & 3;                          // channel block: c*16..c*16+15
    unsigned coff = (unsigned)c << 4;

    int beg = begs[node];
    int end = ends[node];

    float a[16];
#pragma unroll
    for (int j = 0; j < 16; j++) a[j] = 0.f;
    float ssum = 0.f;

    {
        float s = sc[node];
        uint4 u = *(const uint4*)(z + (((unsigned)node) << 6) + coff);
        ssum += s;
        acc16(s, u, a);
    }

    int e = beg;
    while (__any(e < end)) {
        float s0 = 0.f, s1 = 0.f, s2 = 0.f, s3 = 0.f;
        float s4 = 0.f, s5 = 0.f, s6 = 0.f, s7 = 0.f;
        uint4 r0 = {0,0,0,0}, r1 = {0,0,0,0}, r2 = {0,0,0,0}, r3 = {0,0,0,0};
        uint4 r4 = {0,0,0,0}, r5 = {0,0,0,0}, r6 = {0,0,0,0}, r7 = {0,0,0,0};
        if (e     < end) { int i = csr[e    ]; s0 = sc[i]; r0 = *(const uint4*)(z + (((unsigned)i) << 6) + coff); }
        if (e + 1 < end) { int i = csr[e + 1]; s1 = sc[i]; r1 = *(const uint4*)(z + (((unsigned)i) << 6) + coff); }
        if (e + 2 < end) { int i = csr[e + 2]; s2 = sc[i]; r2 = *(const uint4*)(z + (((unsigned)i) << 6) + coff); }
        if (e + 3 < end) { int i = csr[e + 3]; s3 = sc[i]; r3 = *(const uint4*)(z + (((unsigned)i) << 6) + coff); }
        if (e + 4 < end) { int i = csr[e + 4]; s4 = sc[i]; r4 = *(const uint4*)(z + (((unsigned)i) << 6) + coff); }
        if (e + 5 < end) { int i = csr[e + 5]; s5 = sc[i]; r5 = *(const uint4*)(z + (((unsigned)i) << 6) + coff); }
        if (e + 6 < end) { int i = csr[e + 6]; s6 = sc[i]; r6 = *(const uint4*)(z + (((unsigned)i) << 6) + coff); }
        if (e + 7 < end) { int i = csr[e + 7]; s7 = sc[i]; r7 = *(const uint4*)(z + (((unsigned)i) << 6) + coff); }
        ssum += ((s0 + s1) + (s2 + s3)) + ((s4 + s5) + (s6 + s7));
        acc16(s0, r0, a); acc16(s1, r1, a); acc16(s2, r2, a); acc16(s3, r3, a);
        acc16(s4, r4, a); acc16(s5, r5, a); acc16(s6, r6, a); acc16(s7, r7, a);
        e += 8;
    }

    {
        float base = 128.f * ssum;
        float inv = 1.0f / (float)(end - beg + 1);
#pragma unroll
        for (int j = 0; j < 4; j++) {
            float4 bb = ((const float4*)bias)[c * 4 + j];
            out[(long)node * 16 + c * 4 + j] =
                make_float4((a[j * 4 + 0] - base) * inv + bb.x,
                            (a[j * 4 + 1] - base) * inv + bb.y,
                            (a[j * 4 + 2] - base) * inv + bb.z,
                            (a[j * 4 + 3] - base) * inv + bb.w);
        }
    }
}

extern "C" void kernel_launch(void* const* d_in, const int* in_sizes, int n_in,
                              void* d_out, int out_size, void* d_ws, size_t ws_size,
                              hipStream_t stream) {
    const float* feat = (const float*)d_in[0];
    const float* W1   = (const float*)d_in[1];
    const float* b1   = (const float*)d_in[2];
    const float* W2   = (const float*)d_in[3];
    const float* b2   = (const float*)d_in[4];
    const int*   src  = (const int*)d_in[5];
    const int*   dst  = (const int*)d_in[6];
    float* out = (float*)d_out;

    // Workspace layout:
    //   bcur i32[782]            @ 0x0000000
    //   begs i32[100000]         @ 0x0001000
    //   ends i32[100000]         @ 0x0063000
    //   csr4 i32[NB*CAP]         @ 0x00C5000  (8.0 MB)
    //   ebuf i32[NB*CAP]         @ 0x0870000  (8.0 MB)
    //   csr8 int2[NB*CAP]        @ 0x1100000  (16.0 MB)
    //   z1   u8 [12.8M]          @ 0x2100000
    //   sc1  f32[100000]         @ 0x2E00000
    //   z2   u8 [6.4M]           @ 0x2F00000
    //   sc2  f32[100000]         @ 0x3600000
    //   W1t  f16[16384]          @ 0x3700000
    //   W2t  f16[8192]           @ 0x3710000
    char* ws = (char*)d_ws;
    int* bcur = (int*)(ws + 0x0000000);
    int* begs = (int*)(ws + 0x0001000);
    int* ends = (int*)(ws + 0x0063000);
    int* csr4 = (int*)(ws + 0x00C5000);
    int* ebuf = (int*)(ws + 0x0870000);
    int2* csr8 = (int2*)(ws + 0x1100000);
    unsigned char* z1 = (unsigned char*)(ws + 0x2100000);
    float* sc1 = (float*)(ws + 0x2E00000);
    unsigned char* z2 = (unsigned char*)(ws + 0x2F00000);
    float* sc2 = (float*)(ws + 0x3600000);
    f16* W1t  = (f16*)(ws + 0x3700000);
    f16* W2t  = (f16*)(ws + 0x3710000);

    // 1. init cursors + weight prep (no memsets needed anywhere)
    init_k<<<100, 256, 0, stream>>>(bcur, W1, W1t, W2, W2t);

    // 2. edge scatter into padded buckets + layer-1 GEMM (fused)
    scatter_gemm1<<<EBLOCKS + GEMM_BLOCKS, 256, 0, stream>>>(src, dst, bcur, ebuf,
                                                             feat, W1t, z1, sc1);

    // 3. per-bucket CSR fill (csr4 + {src,scale} csr8) + per-node beg/end
    fill_bucket<<<NB, 256, 0, stream>>>(ebuf, bcur, sc1, begs, ends, csr4, csr8);

    // 4. layer-1 gather (+bias+relu) fused with layer-2 projection
    //    128 nodes/block -> 782 blocks
    gather128_gemm2<<<782, 1024, 0, stream>>>(z1, sc1, csr8, begs, ends, b1, W2t,
                                              z2, sc2);

    // 5. layer-2 gather (+bias) -> output; 64 nodes/block -> 1563 blocks
    gather64<<<1563, 256, 0, stream>>>(z2, sc2, begs, ends, csr4, b2, (float4*)out);
}

// Round 8
// 261.136 us; speedup vs baseline: 1.2808x; 1.2808x over previous
//
#include <hip/hip_runtime.h>

#define NNODES 100000
#define NEDGES 1600000
#define BSHIFT 7
#define NB 782            // buckets of 128 nodes: bucket = dst >> 7
#define CAP 2560          // padded per-bucket capacity (mean 2048, +11 sigma)
#define EBLOCKS 391       // edge-scatter blocks (4096 edges each)
#define GEMM_BLOCKS 1563  // (NNODES + 63) / 64

typedef _Float16 f16;
typedef _Float16 v8h __attribute__((ext_vector_type(8)));
typedef float v4f __attribute__((ext_vector_type(4)));

// Single-instruction byte->float decode (v_cvt_f32_ubyteN), with safe fallback.
#if __has_builtin(__builtin_amdgcn_cvt_f32_ubyte0)
#define CVTB0(u) __builtin_amdgcn_cvt_f32_ubyte0(u)
#define CVTB1(u) __builtin_amdgcn_cvt_f32_ubyte1(u)
#define CVTB2(u) __builtin_amdgcn_cvt_f32_ubyte2(u)
#define CVTB3(u) __builtin_amdgcn_cvt_f32_ubyte3(u)
#else
#define CVTB0(u) ((float)((u) & 0xFFu))
#define CVTB1(u) ((float)(((u) >> 8) & 0xFFu))
#define CVTB2(u) ((float)(((u) >> 16) & 0xFFu))
#define CVTB3(u) ((float)((u) >> 24))
#endif

// decode-accumulate 8 bytes (uint2): a[j] += s * byte_j
__device__ inline void acc8(float s, uint2 u, float* a) {
    a[0] = fmaf(s, CVTB0(u.x), a[0]);
    a[1] = fmaf(s, CVTB1(u.x), a[1]);
    a[2] = fmaf(s, CVTB2(u.x), a[2]);
    a[3] = fmaf(s, CVTB3(u.x), a[3]);
    a[4] = fmaf(s, CVTB0(u.y), a[4]);
    a[5] = fmaf(s, CVTB1(u.y), a[5]);
    a[6] = fmaf(s, CVTB2(u.y), a[6]);
    a[7] = fmaf(s, CVTB3(u.y), a[7]);
}

// ---------------------------------------------------------------------------
// Init: bucket cursors (bcur[b] = b*CAP) + weight transpose/convert to f16.
// ---------------------------------------------------------------------------
__global__ __launch_bounds__(256) void init_k(int* __restrict__ bcur,
                                              const float* __restrict__ W1,
                                              f16* __restrict__ W1t,
                                              const float* __restrict__ W2,
                                              f16* __restrict__ W2t) {
    int t = blockIdx.x * 256 + threadIdx.x;
    if (t < NB) bcur[t] = t * CAP;
    int u = t - 1024;
    if (u >= 0) {
        if (u < 128 * 128) {
            int k = u >> 7, n = u & 127;
            W1t[n * 128 + k] = (f16)W1[k * 128 + n];
        } else if (u < 128 * 128 + 128 * 64) {
            int v = u - 128 * 128;
            int k = v >> 6, n = v & 63;
            W2t[n * 128 + k] = (f16)W2[k * 64 + n];
        }
    }
}

// ---------------------------------------------------------------------------
// Fused: edge scatter into bucket-padded ebuf (blocks 0..EBLOCKS-1) +
// layer-1 MFMA GEMM (remaining blocks). z1 stored as per-row-scaled int8
// (biased uint8, 128 B rows) + sc1[node] = rowmax/127.
// ebuf entry packed 4B: src | (dst&127)<<24  (src < 2^17).
// ---------------------------------------------------------------------------
__global__ __launch_bounds__(256) void scatter_gemm1(
    const int* __restrict__ src, const int* __restrict__ dst,
    int* __restrict__ bcur, int* __restrict__ ebuf,
    const float* __restrict__ feat, const f16* __restrict__ W1t,
    unsigned char* __restrict__ z1, float* __restrict__ sc1) {
    constexpr int PITCH = 136;
    __shared__ __align__(16) char smem[128 * PITCH * 2];  // 34816 B
    int tid = threadIdx.x;

    if (blockIdx.x < EBLOCKS) {
        int* h = (int*)smem;
        int* base_s = ((int*)smem) + 1024;
        for (int i = tid; i < NB; i += 256) h[i] = 0;
        __syncthreads();
        int base = blockIdx.x * 4096;
        int d[16], sv[16];
        for (int k = 0; k < 16; k++) {
            int e = base + k * 256 + tid;
            if (e < NEDGES) {
                d[k] = dst[e];
                sv[k] = src[e];
                atomicAdd(&h[d[k] >> BSHIFT], 1);
            } else {
                d[k] = -1;
            }
        }
        __syncthreads();
        for (int i = tid; i < NB; i += 256) {
            int c = h[i];
            if (c) base_s[i] = atomicAdd(&bcur[i], c);
            h[i] = 0;
        }
        __syncthreads();
        for (int k = 0; k < 16; k++) {
            if (d[k] >= 0) {
                int b = d[k] >> BSHIFT;
                int slot = atomicAdd(&h[b], 1);
                ebuf[base_s[b] + slot] = sv[k] | ((d[k] & 127) << 24);
            }
        }
        return;
    }

    // ---- GEMM-1 branch: z1 = int8(f16(feat) @ W1t^T), per-row scale ----
    f16* wlds = (f16*)smem;
    for (int c = tid; c < 128 * 16; c += 256) {
        int n = c >> 4;
        int kc = c & 15;
        *(v8h*)&wlds[n * PITCH + kc * 8] = *(const v8h*)&W1t[n * 128 + kc * 8];
    }
    __syncthreads();

    int wave = tid >> 6, lane = tid & 63, quad = lane >> 4, l16 = lane & 15;
    int m0 = (blockIdx.x - EBLOCKS) * 64 + wave * 16;
    if (m0 >= NNODES) return;  // NNODES % 16 == 0

    v8h a[4];
    const float* arow = feat + (long)(m0 + l16) * 128 + quad * 8;
#pragma unroll
    for (int kb = 0; kb < 4; kb++) {
        float4 f0 = *(const float4*)(arow + kb * 32);
        float4 f1 = *(const float4*)(arow + kb * 32 + 4);
        v8h t = {(f16)f0.x, (f16)f0.y, (f16)f0.z, (f16)f0.w,
                 (f16)f1.x, (f16)f1.y, (f16)f1.z, (f16)f1.w};
        a[kb] = t;
    }

    v4f acc[8];
#pragma unroll
    for (int nt = 0; nt < 8; nt++) {
        v4f c4 = {0.f, 0.f, 0.f, 0.f};
        const f16* brow = &wlds[(nt * 16 + l16) * PITCH + quad * 8];
#pragma unroll
        for (int kb = 0; kb < 4; kb++) {
            v8h b = *(const v8h*)(brow + kb * 32);
            c4 = __builtin_amdgcn_mfma_f32_16x16x32_f16(a[kb], b, c4, 0, 0, 0);
        }
        acc[nt] = c4;
    }

    // per-row (quad,r) max over 8 nt (lane) x 16 l16 lanes, then int8 encode
#pragma unroll
    for (int r = 0; r < 4; r++) {
        float m = 0.f;
#pragma unroll
        for (int nt = 0; nt < 8; nt++) m = fmaxf(m, fabsf(acc[nt][r]));
        m = fmaxf(m, __shfl_xor(m, 1));
        m = fmaxf(m, __shfl_xor(m, 2));
        m = fmaxf(m, __shfl_xor(m, 4));
        m = fmaxf(m, __shfl_xor(m, 8));
        int row = m0 + quad * 4 + r;
        float rs = (m > 0.f) ? 127.f / m : 0.f;
        if (l16 == 0) sc1[row] = (m > 0.f) ? m / 127.f : 0.f;
#pragma unroll
        for (int nt = 0; nt < 8; nt++) {
            int qv = (int)rintf(acc[nt][r] * rs) + 128;
            z1[(long)row * 128 + nt * 16 + l16] = (unsigned char)qv;
        }
    }
}

// ---------------------------------------------------------------------------
// Per-bucket CSR fill (padded layout). Emits:
//   csr4[pos] = src                   (for gather64; its scales are sc2,
//                                      which don't exist yet -> per-edge load)
//   csr8[pos] = {src, f32 sc1[src]}   (for gather128: correct z1 scale packed
//                                      with the index -> one 8B broadcast)
// ---------------------------------------------------------------------------
__global__ __launch_bounds__(256) void fill_bucket(const int* __restrict__ ebuf,
                                                   const int* __restrict__ bcur,
                                                   const float* __restrict__ sc1,
                                                   int* __restrict__ begs,
                                                   int* __restrict__ ends,
                                                   int* __restrict__ csr4,
                                                   int2* __restrict__ csr8) {
    __shared__ int lc[128];
    __shared__ int ls[256];
    int b = blockIdx.x;
    int tid = threadIdx.x;
    if (tid < 128) lc[tid] = 0;
    __syncthreads();
    int ebeg = b * CAP;
    int eend = bcur[b];  // = b*CAP + bucket count
    for (int e = ebeg + tid; e < eend; e += 256)
        atomicAdd(&lc[((unsigned)ebuf[e]) >> 24], 1);
    __syncthreads();
    int cnt = (tid < 128) ? lc[tid] : 0;
    ls[tid] = cnt;
    __syncthreads();
    for (int off = 1; off < 256; off <<= 1) {
        int t = (tid >= off) ? ls[tid - off] : 0;
        __syncthreads();
        ls[tid] += t;
        __syncthreads();
    }
    int excl = ls[tid] - cnt;
    int node = (b << BSHIFT) + tid;
    if (tid < 128 && node < NNODES) {
        begs[node] = ebeg + excl;
        ends[node] = ebeg + excl + cnt;
    }
    if (tid < 128) { ls[tid] = excl; lc[tid] = 0; }
    __syncthreads();
    for (int e = ebeg + tid; e < eend; e += 256) {
        int p = ebuf[e];
        int dloc = ((unsigned)p) >> 24;
        int s = p & 0xFFFFFF;
        int slot = atomicAdd(&lc[dloc], 1);
        int pos = ebeg + ls[dloc] + slot;
        csr4[pos] = s;
        csr8[pos] = make_int2(s, __float_as_int(sc1[s]));
    }
}

// ---------------------------------------------------------------------------
// Fused layer-1 gather + layer-2 projection, SUBGROUP-PER-NODE, int8 rows.
// Round-5 register footprint (NO spills): 16-lane subgroups, uint2 row
// chunks, a[8] accumulators (~40 live VGPRs, under the 64 cap of
// __launch_bounds__(1024,8)). csr8 {src,scale} broadcast load replaces
// csr+sc (24 -> 16 VMEM/iter); decode is guaranteed v_cvt_f32_ubyteN.
// Bias identity: sum = SUM s_i*(q_i+128) - 128*SUM s_i (masked edges s=0).
// h1 -> f16 atile[64] -> 16-wave 64x64 MFMA epilogue -> z2 int8 + sc2.
// ---------------------------------------------------------------------------
__global__ __launch_bounds__(1024, 8) void gather128_gemm2(
    const unsigned char* __restrict__ z,  // z1, 128 B int8 rows
    const float* __restrict__ sc,         // sc1[NNODES] (self term)
    const int2* __restrict__ csr8,        // {src, f32 sc1-scale}
    const int* __restrict__ begs, const int* __restrict__ ends,
    const float* __restrict__ b1,     // [128]
    const f16* __restrict__ W2t,      // [64,128]
    unsigned char* __restrict__ z2,   // [NNODES,64] int8
    float* __restrict__ sc2)          // sc2[NNODES]
{
    constexpr int PITCH = 136;
    __shared__ f16 w2lds[64 * PITCH];   // 17408 B
    __shared__ f16 atile[64 * PITCH];   // 17408 B
    __shared__ int rmax[64];
    int tid = threadIdx.x;

    // stage W2t (1024 threads, exactly 64*16 8-half chunks)
    {
        int n = tid >> 4, kc = tid & 15;
        *(v8h*)&w2lds[n * PITCH + kc * 8] = *(const v8h*)&W2t[n * 128 + kc * 8];
    }
    if (tid < 64) rmax[tid] = 0;

    int wavei = tid >> 6;   // wave 0..15
    int lane = tid & 63;
    int sub = lane >> 4;    // subgroup 0..3 (one node each)
    int c = lane & 15;      // channel block: c*8 .. c*8+7
    int lnode = wavei * 4 + sub;             // 0..63
    int node = blockIdx.x * 64 + lnode;

    int beg = 0, end = 0;
    if (node < NNODES) { beg = begs[node]; end = ends[node]; }

    unsigned coff = (unsigned)c << 3;   // byte offset of this lane's 8B chunk

    float a[8];
#pragma unroll
    for (int j = 0; j < 8; j++) a[j] = 0.f;
    float ssum = 0.f;

    // self row: all 64 lanes active
    if (node < NNODES) {
        float s = sc[node];
        uint2 u = *(const uint2*)(z + (((unsigned)node) << 7) + coff);
        ssum += s;
        acc8(s, u, a);
    }

    int e = beg;
    while (__any(e < end)) {
        int2 q0 = {0, 0}, q1 = {0, 0}, q2 = {0, 0}, q3 = {0, 0};
        int2 q4 = {0, 0}, q5 = {0, 0}, q6 = {0, 0}, q7 = {0, 0};
        if (e     < end) q0 = csr8[e];
        if (e + 1 < end) q1 = csr8[e + 1];
        if (e + 2 < end) q2 = csr8[e + 2];
        if (e + 3 < end) q3 = csr8[e + 3];
        if (e + 4 < end) q4 = csr8[e + 4];
        if (e + 5 < end) q5 = csr8[e + 5];
        if (e + 6 < end) q6 = csr8[e + 6];
        if (e + 7 < end) q7 = csr8[e + 7];
        uint2 u0 = make_uint2(0, 0), u1 = make_uint2(0, 0);
        uint2 u2 = make_uint2(0, 0), u3 = make_uint2(0, 0);
        uint2 u4 = make_uint2(0, 0), u5 = make_uint2(0, 0);
        uint2 u6 = make_uint2(0, 0), u7 = make_uint2(0, 0);
        if (e     < end) u0 = *(const uint2*)(z + (((unsigned)q0.x) << 7) + coff);
        if (e + 1 < end) u1 = *(const uint2*)(z + (((unsigned)q1.x) << 7) + coff);
        if (e + 2 < end) u2 = *(const uint2*)(z + (((unsigned)q2.x) << 7) + coff);
        if (e + 3 < end) u3 = *(const uint2*)(z + (((unsigned)q3.x) << 7) + coff);
        if (e + 4 < end) u4 = *(const uint2*)(z + (((unsigned)q4.x) << 7) + coff);
        if (e + 5 < end) u5 = *(const uint2*)(z + (((unsigned)q5.x) << 7) + coff);
        if (e + 6 < end) u6 = *(const uint2*)(z + (((unsigned)q6.x) << 7) + coff);
        if (e + 7 < end) u7 = *(const uint2*)(z + (((unsigned)q7.x) << 7) + coff);
        float s0 = __int_as_float(q0.y), s1 = __int_as_float(q1.y);
        float s2 = __int_as_float(q2.y), s3 = __int_as_float(q3.y);
        float s4 = __int_as_float(q4.y), s5 = __int_as_float(q5.y);
        float s6 = __int_as_float(q6.y), s7 = __int_as_float(q7.y);
        ssum += ((s0 + s1) + (s2 + s3)) + ((s4 + s5) + (s6 + s7));
        acc8(s0, u0, a); acc8(s1, u1, a); acc8(s2, u2, a); acc8(s3, u3, a);
        acc8(s4, u4, a); acc8(s5, u5, a); acc8(s6, u6, a); acc8(s7, u7, a);
        e += 8;
    }

    // normalize + bias + relu -> atile (no cross-lane reduce needed)
    {
        float base = 128.f * ssum;
        float inv = 1.0f / (float)(end - beg + 1);
        float4 bb0 = ((const float4*)b1)[c * 2];
        float4 bb1 = ((const float4*)b1)[c * 2 + 1];
        v8h o = {(f16)fmaxf((a[0] - base) * inv + bb0.x, 0.f),
                 (f16)fmaxf((a[1] - base) * inv + bb0.y, 0.f),
                 (f16)fmaxf((a[2] - base) * inv + bb0.z, 0.f),
                 (f16)fmaxf((a[3] - base) * inv + bb0.w, 0.f),
                 (f16)fmaxf((a[4] - base) * inv + bb1.x, 0.f),
                 (f16)fmaxf((a[5] - base) * inv + bb1.y, 0.f),
                 (f16)fmaxf((a[6] - base) * inv + bb1.z, 0.f),
                 (f16)fmaxf((a[7] - base) * inv + bb1.w, 0.f)};
        *(v8h*)&atile[lnode * PITCH + c * 8] = o;
    }
    __syncthreads();

    // ---- epilogue: z2[64 rows] = int8(atile @ W2t^T); wave w -> tile (w>>2, w&3)
    {
        int wr = wavei >> 2, wc = wavei & 3;
        int quad = lane >> 4, l16 = lane & 15;
        const f16* arow = &atile[(wr * 16 + l16) * PITCH + quad * 8];
        const f16* brow = &w2lds[(wc * 16 + l16) * PITCH + quad * 8];
        v4f acc = {0.f, 0.f, 0.f, 0.f};
#pragma unroll
        for (int kb = 0; kb < 4; kb++) {
            v8h av = *(const v8h*)(arow + kb * 32);
            v8h bv = *(const v8h*)(brow + kb * 32);
            acc = __builtin_amdgcn_mfma_f32_16x16x32_f16(av, bv, acc, 0, 0, 0);
        }
        // per-row |max| across 16 l16 lanes, then across the 4 wc waves
#pragma unroll
        for (int r = 0; r < 4; r++) {
            float m = fabsf(acc[r]);
            m = fmaxf(m, __shfl_xor(m, 1));
            m = fmaxf(m, __shfl_xor(m, 2));
            m = fmaxf(m, __shfl_xor(m, 4));
            m = fmaxf(m, __shfl_xor(m, 8));
            if (l16 == 0) atomicMax(&rmax[wr * 16 + quad * 4 + r], __float_as_int(m));
        }
        __syncthreads();
#pragma unroll
        for (int r = 0; r < 4; r++) {
            int lrow = wr * 16 + quad * 4 + r;
            int row = blockIdx.x * 64 + lrow;
            if (row < NNODES) {
                float m = __int_as_float(rmax[lrow]);
                float rs = (m > 0.f) ? 127.f / m : 0.f;
                int qv = (int)rintf(acc[r] * rs) + 128;
                z2[(long)row * 64 + wc * 16 + l16] = (unsigned char)qv;
                if (l16 == 0 && wc == 0) sc2[row] = (m > 0.f) ? m / 127.f : 0.f;
            }
        }
    }
}

// ---------------------------------------------------------------------------
// Layer-2 gather+normalize, SUBGROUP-PER-NODE, int8 rows: wave = 8x 8-lane
// subgroups, one node per subgroup (8 lanes x 8B = full 64B int8 z2 row =
// ONE cache line per gather). csr4 index + per-edge sc2 load (sc2 is 400KB,
// L2-resident; csr8's packed scale is sc1 -- WRONG layer here, round-7 bug).
// ---------------------------------------------------------------------------
__global__ __launch_bounds__(256, 8) void gather64(
    const unsigned char* __restrict__ z, const float* __restrict__ sc,
    const int* __restrict__ begs, const int* __restrict__ ends,
    const int* __restrict__ csr,
    const float* __restrict__ bias, float4* __restrict__ out) {
    int tid = threadIdx.x;
    int lane = tid & 63;
    int c = lane & 7;                         // channel block: c*8..c*8+7
    int node = blockIdx.x * 32 + (tid >> 3);  // 3125*32 == NNODES exactly

    int beg = begs[node];
    int end = ends[node];

    unsigned coff = (unsigned)c << 3;

    float a[8];
#pragma unroll
    for (int j = 0; j < 8; j++) a[j] = 0.f;
    float ssum = 0.f;

    {
        float s = sc[node];
        uint2 u = *(const uint2*)(z + (((unsigned)node) << 6) + coff);
        ssum += s;
        acc8(s, u, a);
    }

    int e = beg;
    while (__any(e < end)) {
        float s0 = 0.f, s1 = 0.f, s2 = 0.f, s3 = 0.f;
        float s4 = 0.f, s5 = 0.f, s6 = 0.f, s7 = 0.f;
        uint2 u0 = make_uint2(0, 0), u1 = make_uint2(0, 0);
        uint2 u2 = make_uint2(0, 0), u3 = make_uint2(0, 0);
        uint2 u4 = make_uint2(0, 0), u5 = make_uint2(0, 0);
        uint2 u6 = make_uint2(0, 0), u7 = make_uint2(0, 0);
        if (e     < end) { int i = csr[e    ]; s0 = sc[i]; u0 = *(const uint2*)(z + (((unsigned)i) << 6) + coff); }
        if (e + 1 < end) { int i = csr[e + 1]; s1 = sc[i]; u1 = *(const uint2*)(z + (((unsigned)i) << 6) + coff); }
        if (e + 2 < end) { int i = csr[e + 2]; s2 = sc[i]; u2 = *(const uint2*)(z + (((unsigned)i) << 6) + coff); }
        if (e + 3 < end) { int i = csr[e + 3]; s3 = sc[i]; u3 = *(const uint2*)(z + (((unsigned)i) << 6) + coff); }
        if (e + 4 < end) { int i = csr[e + 4]; s4 = sc[i]; u4 = *(const uint2*)(z + (((unsigned)i) << 6) + coff); }
        if (e + 5 < end) { int i = csr[e + 5]; s5 = sc[i]; u5 = *(const uint2*)(z + (((unsigned)i) << 6) + coff); }
        if (e + 6 < end) { int i = csr[e + 6]; s6 = sc[i]; u6 = *(const uint2*)(z + (((unsigned)i) << 6) + coff); }
        if (e + 7 < end) { int i = csr[e + 7]; s7 = sc[i]; u7 = *(const uint2*)(z + (((unsigned)i) << 6) + coff); }
        ssum += ((s0 + s1) + (s2 + s3)) + ((s4 + s5) + (s6 + s7));
        acc8(s0, u0, a); acc8(s1, u1, a); acc8(s2, u2, a); acc8(s3, u3, a);
        acc8(s4, u4, a); acc8(s5, u5, a); acc8(s6, u6, a); acc8(s7, u7, a);
        e += 8;
    }

    {
        float base = 128.f * ssum;
        float inv = 1.0f / (float)(end - beg + 1);
        float4 b0 = ((const float4*)bias)[c * 2];
        float4 b1v = ((const float4*)bias)[c * 2 + 1];
        out[(long)node * 16 + c * 2] =
            make_float4((a[0] - base) * inv + b0.x, (a[1] - base) * inv + b0.y,
                        (a[2] - base) * inv + b0.z, (a[3] - base) * inv + b0.w);
        out[(long)node * 16 + c * 2 + 1] =
            make_float4((a[4] - base) * inv + b1v.x, (a[5] - base) * inv + b1v.y,
                        (a[6] - base) * inv + b1v.z, (a[7] - base) * inv + b1v.w);
    }
}

extern "C" void kernel_launch(void* const* d_in, const int* in_sizes, int n_in,
                              void* d_out, int out_size, void* d_ws, size_t ws_size,
                              hipStream_t stream) {
    const float* feat = (const float*)d_in[0];
    const float* W1   = (const float*)d_in[1];
    const float* b1   = (const float*)d_in[2];
    const float* W2   = (const float*)d_in[3];
    const float* b2   = (const float*)d_in[4];
    const int*   src  = (const int*)d_in[5];
    const int*   dst  = (const int*)d_in[6];
    float* out = (float*)d_out;

    // Workspace layout:
    //   bcur i32[782]            @ 0x0000000
    //   begs i32[100000]         @ 0x0001000
    //   ends i32[100000]         @ 0x0063000
    //   ebuf i32[NB*CAP]         @ 0x00C5000  (8.0 MB)
    //   csr4 i32[NB*CAP]         @ 0x0900000  (8.0 MB)
    //   csr8 int2[NB*CAP]        @ 0x1100000  (16.0 MB)
    //   z1   u8 [12.8M]          @ 0x2100000
    //   sc1  f32[100000]         @ 0x2E00000
    //   z2   u8 [6.4M]           @ 0x2F00000
    //   sc2  f32[100000]         @ 0x3600000
    //   W1t  f16[16384]          @ 0x3700000
    //   W2t  f16[8192]           @ 0x3710000
    char* ws = (char*)d_ws;
    int* bcur = (int*)(ws + 0x0000000);
    int* begs = (int*)(ws + 0x0001000);
    int* ends = (int*)(ws + 0x0063000);
    int* ebuf = (int*)(ws + 0x00C5000);
    int* csr4 = (int*)(ws + 0x0900000);
    int2* csr8 = (int2*)(ws + 0x1100000);
    unsigned char* z1 = (unsigned char*)(ws + 0x2100000);
    float* sc1 = (float*)(ws + 0x2E00000);
    unsigned char* z2 = (unsigned char*)(ws + 0x2F00000);
    float* sc2 = (float*)(ws + 0x3600000);
    f16* W1t  = (f16*)(ws + 0x3700000);
    f16* W2t  = (f16*)(ws + 0x3710000);

    // 1. init cursors + weight prep (no memsets needed anywhere)
    init_k<<<100, 256, 0, stream>>>(bcur, W1, W1t, W2, W2t);

    // 2. edge scatter into padded buckets + layer-1 GEMM (fused)
    scatter_gemm1<<<EBLOCKS + GEMM_BLOCKS, 256, 0, stream>>>(src, dst, bcur, ebuf,
                                                             feat, W1t, z1, sc1);

    // 3. per-bucket CSR fill (csr4 + {src,sc1} csr8) + per-node beg/end
    fill_bucket<<<NB, 256, 0, stream>>>(ebuf, bcur, sc1, begs, ends, csr4, csr8);

    // 4. layer-1 gather (+bias+relu) fused with layer-2 projection
    //    64 nodes/block -> 1563 blocks
    gather128_gemm2<<<1563, 1024, 0, stream>>>(z1, sc1, csr8, begs, ends, b1, W2t,
                                               z2, sc2);

    // 5. layer-2 gather (+bias) -> output; 32 nodes/block, 3125*32 = 100000
    gather64<<<3125, 256, 0, stream>>>(z2, sc2, begs, ends, csr4, b2, (float4*)out);
}

// Round 9
// 247.756 us; speedup vs baseline: 1.3499x; 1.0540x over previous
//
#include <hip/hip_runtime.h>

#define NNODES 100000
#define NEDGES 1600000
#define BSHIFT 7
#define NB 782            // buckets of 128 nodes: bucket = dst >> 7
#define CAP 2560          // padded per-bucket capacity (mean 2048, +11 sigma)
#define EBLOCKS 391       // edge-scatter blocks (4096 edges each)
#define GEMM_BLOCKS 1563  // (NNODES + 63) / 64

typedef _Float16 f16;
typedef _Float16 v8h __attribute__((ext_vector_type(8)));
typedef float v4f __attribute__((ext_vector_type(4)));

// Single-instruction byte->float decode (v_cvt_f32_ubyteN), with safe fallback.
#if __has_builtin(__builtin_amdgcn_cvt_f32_ubyte0)
#define CVTB0(u) __builtin_amdgcn_cvt_f32_ubyte0(u)
#define CVTB1(u) __builtin_amdgcn_cvt_f32_ubyte1(u)
#define CVTB2(u) __builtin_amdgcn_cvt_f32_ubyte2(u)
#define CVTB3(u) __builtin_amdgcn_cvt_f32_ubyte3(u)
#else
#define CVTB0(u) ((float)((u) & 0xFFu))
#define CVTB1(u) ((float)(((u) >> 8) & 0xFFu))
#define CVTB2(u) ((float)(((u) >> 16) & 0xFFu))
#define CVTB3(u) ((float)((u) >> 24))
#endif

// decode-accumulate 8 bytes (uint2): a[j] += s * byte_j
__device__ inline void acc8(float s, uint2 u, float* a) {
    a[0] = fmaf(s, CVTB0(u.x), a[0]);
    a[1] = fmaf(s, CVTB1(u.x), a[1]);
    a[2] = fmaf(s, CVTB2(u.x), a[2]);
    a[3] = fmaf(s, CVTB3(u.x), a[3]);
    a[4] = fmaf(s, CVTB0(u.y), a[4]);
    a[5] = fmaf(s, CVTB1(u.y), a[5]);
    a[6] = fmaf(s, CVTB2(u.y), a[6]);
    a[7] = fmaf(s, CVTB3(u.y), a[7]);
}

// ---------------------------------------------------------------------------
// Init: bucket cursors (bcur[b] = b*CAP) + weight transpose/convert to f16.
// ---------------------------------------------------------------------------
__global__ __launch_bounds__(256) void init_k(int* __restrict__ bcur,
                                              const float* __restrict__ W1,
                                              f16* __restrict__ W1t,
                                              const float* __restrict__ W2,
                                              f16* __restrict__ W2t) {
    int t = blockIdx.x * 256 + threadIdx.x;
    if (t < NB) bcur[t] = t * CAP;
    int u = t - 1024;
    if (u >= 0) {
        if (u < 128 * 128) {
            int k = u >> 7, n = u & 127;
            W1t[n * 128 + k] = (f16)W1[k * 128 + n];
        } else if (u < 128 * 128 + 128 * 64) {
            int v = u - 128 * 128;
            int k = v >> 6, n = v & 63;
            W2t[n * 128 + k] = (f16)W2[k * 64 + n];
        }
    }
}

// ---------------------------------------------------------------------------
// Fused: edge scatter into bucket-padded ebuf (blocks 0..EBLOCKS-1) +
// layer-1 MFMA GEMM (remaining blocks). z1 stored as per-row-scaled int8
// (biased uint8, 128 B rows) + sc1[node] = rowmax/127.
// ebuf entry packed 4B: src | (dst&127)<<24  (src < 2^17).
// ---------------------------------------------------------------------------
__global__ __launch_bounds__(256) void scatter_gemm1(
    const int* __restrict__ src, const int* __restrict__ dst,
    int* __restrict__ bcur, int* __restrict__ ebuf,
    const float* __restrict__ feat, const f16* __restrict__ W1t,
    unsigned char* __restrict__ z1, float* __restrict__ sc1) {
    constexpr int PITCH = 136;
    __shared__ __align__(16) char smem[128 * PITCH * 2];  // 34816 B
    int tid = threadIdx.x;

    if (blockIdx.x < EBLOCKS) {
        int* h = (int*)smem;
        int* base_s = ((int*)smem) + 1024;
        for (int i = tid; i < NB; i += 256) h[i] = 0;
        __syncthreads();
        int base = blockIdx.x * 4096;
        int d[16], sv[16];
        for (int k = 0; k < 16; k++) {
            int e = base + k * 256 + tid;
            if (e < NEDGES) {
                d[k] = dst[e];
                sv[k] = src[e];
                atomicAdd(&h[d[k] >> BSHIFT], 1);
            } else {
                d[k] = -1;
            }
        }
        __syncthreads();
        for (int i = tid; i < NB; i += 256) {
            int c = h[i];
            if (c) base_s[i] = atomicAdd(&bcur[i], c);
            h[i] = 0;
        }
        __syncthreads();
        for (int k = 0; k < 16; k++) {
            if (d[k] >= 0) {
                int b = d[k] >> BSHIFT;
                int slot = atomicAdd(&h[b], 1);
                ebuf[base_s[b] + slot] = sv[k] | ((d[k] & 127) << 24);
            }
        }
        return;
    }

    // ---- GEMM-1 branch: z1 = int8(f16(feat) @ W1t^T), per-row scale ----
    f16* wlds = (f16*)smem;
    for (int c = tid; c < 128 * 16; c += 256) {
        int n = c >> 4;
        int kc = c & 15;
        *(v8h*)&wlds[n * PITCH + kc * 8] = *(const v8h*)&W1t[n * 128 + kc * 8];
    }
    __syncthreads();

    int wave = tid >> 6, lane = tid & 63, quad = lane >> 4, l16 = lane & 15;
    int m0 = (blockIdx.x - EBLOCKS) * 64 + wave * 16;
    if (m0 >= NNODES) return;  // NNODES % 16 == 0

    v8h a[4];
    const float* arow = feat + (long)(m0 + l16) * 128 + quad * 8;
#pragma unroll
    for (int kb = 0; kb < 4; kb++) {
        float4 f0 = *(const float4*)(arow + kb * 32);
        float4 f1 = *(const float4*)(arow + kb * 32 + 4);
        v8h t = {(f16)f0.x, (f16)f0.y, (f16)f0.z, (f16)f0.w,
                 (f16)f1.x, (f16)f1.y, (f16)f1.z, (f16)f1.w};
        a[kb] = t;
    }

    v4f acc[8];
#pragma unroll
    for (int nt = 0; nt < 8; nt++) {
        v4f c4 = {0.f, 0.f, 0.f, 0.f};
        const f16* brow = &wlds[(nt * 16 + l16) * PITCH + quad * 8];
#pragma unroll
        for (int kb = 0; kb < 4; kb++) {
            v8h b = *(const v8h*)(brow + kb * 32);
            c4 = __builtin_amdgcn_mfma_f32_16x16x32_f16(a[kb], b, c4, 0, 0, 0);
        }
        acc[nt] = c4;
    }

    // per-row (quad,r) max over 8 nt (lane) x 16 l16 lanes, then int8 encode
#pragma unroll
    for (int r = 0; r < 4; r++) {
        float m = 0.f;
#pragma unroll
        for (int nt = 0; nt < 8; nt++) m = fmaxf(m, fabsf(acc[nt][r]));
        m = fmaxf(m, __shfl_xor(m, 1));
        m = fmaxf(m, __shfl_xor(m, 2));
        m = fmaxf(m, __shfl_xor(m, 4));
        m = fmaxf(m, __shfl_xor(m, 8));
        int row = m0 + quad * 4 + r;
        float rs = (m > 0.f) ? 127.f / m : 0.f;
        if (l16 == 0) sc1[row] = (m > 0.f) ? m / 127.f : 0.f;
#pragma unroll
        for (int nt = 0; nt < 8; nt++) {
            int qv = (int)rintf(acc[nt][r] * rs) + 128;
            z1[(long)row * 128 + nt * 16 + l16] = (unsigned char)qv;
        }
    }
}

// ---------------------------------------------------------------------------
// Per-bucket CSR fill (padded layout). Emits csr8[pos] = {src, f32 sc1[src]}.
// gather128_h1 uses both fields; gather64 uses .x only (its scales are sc2,
// loaded per-edge there -- sc1 packed here is layer-1-only, round-7 lesson).
// ---------------------------------------------------------------------------
__global__ __launch_bounds__(256) void fill_bucket(const int* __restrict__ ebuf,
                                                   const int* __restrict__ bcur,
                                                   const float* __restrict__ sc1,
                                                   int* __restrict__ begs,
                                                   int* __restrict__ ends,
                                                   int2* __restrict__ csr8) {
    __shared__ int lc[128];
    __shared__ int ls[256];
    int b = blockIdx.x;
    int tid = threadIdx.x;
    if (tid < 128) lc[tid] = 0;
    __syncthreads();
    int ebeg = b * CAP;
    int eend = bcur[b];  // = b*CAP + bucket count
    for (int e = ebeg + tid; e < eend; e += 256)
        atomicAdd(&lc[((unsigned)ebuf[e]) >> 24], 1);
    __syncthreads();
    int cnt = (tid < 128) ? lc[tid] : 0;
    ls[tid] = cnt;
    __syncthreads();
    for (int off = 1; off < 256; off <<= 1) {
        int t = (tid >= off) ? ls[tid - off] : 0;
        __syncthreads();
        ls[tid] += t;
        __syncthreads();
    }
    int excl = ls[tid] - cnt;
    int node = (b << BSHIFT) + tid;
    if (tid < 128 && node < NNODES) {
        begs[node] = ebeg + excl;
        ends[node] = ebeg + excl + cnt;
    }
    if (tid < 128) { ls[tid] = excl; lc[tid] = 0; }
    __syncthreads();
    for (int e = ebeg + tid; e < eend; e += 256) {
        int p = ebuf[e];
        int dloc = ((unsigned)p) >> 24;
        int s = p & 0xFFFFFF;
        int slot = atomicAdd(&lc[dloc], 1);
        csr8[ebeg + ls[dloc] + slot] = make_int2(s, __float_as_int(sc1[s]));
    }
}

// ---------------------------------------------------------------------------
// Layer-1 gather -> h1 (f16), BARRIER-FREE + LDS-FREE. 256-thread blocks =
// 16 independent 16-lane subgroups, one node each. No __syncthreads, no
// epilogue: waves retire as they finish, 8 blocks/CU keep the CU fed past
// stragglers (the fused version held 16 waves + half the CU behind
// E[max deg of 64 nodes]~29). Decode: v_cvt_f32_ubyteN + bias identity.
// ---------------------------------------------------------------------------
__global__ __launch_bounds__(256, 8) void gather128_h1(
    const unsigned char* __restrict__ z,  // z1, 128 B int8 rows
    const float* __restrict__ sc,         // sc1[NNODES] (self term)
    const int2* __restrict__ csr8,        // {src, f32 sc1-scale}
    const int* __restrict__ begs, const int* __restrict__ ends,
    const float* __restrict__ b1,     // [128]
    f16* __restrict__ h1)             // [NNODES,128] f16
{
    int tid = threadIdx.x;
    int c = tid & 15;                         // channel block: c*8 .. c*8+7
    int node = blockIdx.x * 16 + (tid >> 4);  // 6250*16 == NNODES exactly

    int beg = begs[node];
    int end = ends[node];

    unsigned coff = (unsigned)c << 3;   // byte offset of this lane's 8B chunk

    float a[8];
#pragma unroll
    for (int j = 0; j < 8; j++) a[j] = 0.f;
    float ssum = 0.f;

    // self row
    {
        float s = sc[node];
        uint2 u = *(const uint2*)(z + (((unsigned)node) << 7) + coff);
        ssum += s;
        acc8(s, u, a);
    }

    int e = beg;
    while (__any(e < end)) {
        int2 q0 = {0, 0}, q1 = {0, 0}, q2 = {0, 0}, q3 = {0, 0};
        int2 q4 = {0, 0}, q5 = {0, 0}, q6 = {0, 0}, q7 = {0, 0};
        if (e     < end) q0 = csr8[e];
        if (e + 1 < end) q1 = csr8[e + 1];
        if (e + 2 < end) q2 = csr8[e + 2];
        if (e + 3 < end) q3 = csr8[e + 3];
        if (e + 4 < end) q4 = csr8[e + 4];
        if (e + 5 < end) q5 = csr8[e + 5];
        if (e + 6 < end) q6 = csr8[e + 6];
        if (e + 7 < end) q7 = csr8[e + 7];
        uint2 u0 = make_uint2(0, 0), u1 = make_uint2(0, 0);
        uint2 u2 = make_uint2(0, 0), u3 = make_uint2(0, 0);
        uint2 u4 = make_uint2(0, 0), u5 = make_uint2(0, 0);
        uint2 u6 = make_uint2(0, 0), u7 = make_uint2(0, 0);
        if (e     < end) u0 = *(const uint2*)(z + (((unsigned)q0.x) << 7) + coff);
        if (e + 1 < end) u1 = *(const uint2*)(z + (((unsigned)q1.x) << 7) + coff);
        if (e + 2 < end) u2 = *(const uint2*)(z + (((unsigned)q2.x) << 7) + coff);
        if (e + 3 < end) u3 = *(const uint2*)(z + (((unsigned)q3.x) << 7) + coff);
        if (e + 4 < end) u4 = *(const uint2*)(z + (((unsigned)q4.x) << 7) + coff);
        if (e + 5 < end) u5 = *(const uint2*)(z + (((unsigned)q5.x) << 7) + coff);
        if (e + 6 < end) u6 = *(const uint2*)(z + (((unsigned)q6.x) << 7) + coff);
        if (e + 7 < end) u7 = *(const uint2*)(z + (((unsigned)q7.x) << 7) + coff);
        float s0 = __int_as_float(q0.y), s1 = __int_as_float(q1.y);
        float s2 = __int_as_float(q2.y), s3 = __int_as_float(q3.y);
        float s4 = __int_as_float(q4.y), s5 = __int_as_float(q5.y);
        float s6 = __int_as_float(q6.y), s7 = __int_as_float(q7.y);
        ssum += ((s0 + s1) + (s2 + s3)) + ((s4 + s5) + (s6 + s7));
        acc8(s0, u0, a); acc8(s1, u1, a); acc8(s2, u2, a); acc8(s3, u3, a);
        acc8(s4, u4, a); acc8(s5, u5, a); acc8(s6, u6, a); acc8(s7, u7, a);
        e += 8;
    }

    // normalize + bias + relu -> h1 row (coalesced 256B per subgroup)
    {
        float base = 128.f * ssum;
        float inv = 1.0f / (float)(end - beg + 1);
        float4 bb0 = ((const float4*)b1)[c * 2];
        float4 bb1 = ((const float4*)b1)[c * 2 + 1];
        v8h o = {(f16)fmaxf((a[0] - base) * inv + bb0.x, 0.f),
                 (f16)fmaxf((a[1] - base) * inv + bb0.y, 0.f),
                 (f16)fmaxf((a[2] - base) * inv + bb0.z, 0.f),
                 (f16)fmaxf((a[3] - base) * inv + bb0.w, 0.f),
                 (f16)fmaxf((a[4] - base) * inv + bb1.x, 0.f),
                 (f16)fmaxf((a[5] - base) * inv + bb1.y, 0.f),
                 (f16)fmaxf((a[6] - base) * inv + bb1.z, 0.f),
                 (f16)fmaxf((a[7] - base) * inv + bb1.w, 0.f)};
        *(v8h*)&h1[(long)node * 128 + c * 8] = o;
    }
}

// ---------------------------------------------------------------------------
// Standalone layer-2 projection: z2 = int8(h1 @ W2t^T) + sc2. Same structure
// as scatter_gemm1's GEMM (4 waves x 16 rows, W2t in LDS, f16 A loads from
// h1 -- no conversion needed), 4 n-tiles (64-wide out), shfl rowmax encode.
// ---------------------------------------------------------------------------
__global__ __launch_bounds__(256) void gemm2_k(
    const f16* __restrict__ h1,       // [NNODES,128]
    const f16* __restrict__ W2t,      // [64,128]
    unsigned char* __restrict__ z2,   // [NNODES,64] int8
    float* __restrict__ sc2)          // sc2[NNODES]
{
    constexpr int PITCH = 136;
    __shared__ f16 wlds[64 * PITCH];  // 17408 B
    int tid = threadIdx.x;
    for (int c = tid; c < 64 * 16; c += 256) {
        int n = c >> 4;
        int kc = c & 15;
        *(v8h*)&wlds[n * PITCH + kc * 8] = *(const v8h*)&W2t[n * 128 + kc * 8];
    }
    __syncthreads();

    int wave = tid >> 6, lane = tid & 63, quad = lane >> 4, l16 = lane & 15;
    int m0 = blockIdx.x * 64 + wave * 16;
    if (m0 >= NNODES) return;  // NNODES % 16 == 0

    v8h a[4];
    const f16* arow = h1 + (long)(m0 + l16) * 128 + quad * 8;
#pragma unroll
    for (int kb = 0; kb < 4; kb++) a[kb] = *(const v8h*)(arow + kb * 32);

    v4f acc[4];
#pragma unroll
    for (int nt = 0; nt < 4; nt++) {
        v4f c4 = {0.f, 0.f, 0.f, 0.f};
        const f16* brow = &wlds[(nt * 16 + l16) * PITCH + quad * 8];
#pragma unroll
        for (int kb = 0; kb < 4; kb++) {
            v8h b = *(const v8h*)(brow + kb * 32);
            c4 = __builtin_amdgcn_mfma_f32_16x16x32_f16(a[kb], b, c4, 0, 0, 0);
        }
        acc[nt] = c4;
    }

#pragma unroll
    for (int r = 0; r < 4; r++) {
        float m = 0.f;
#pragma unroll
        for (int nt = 0; nt < 4; nt++) m = fmaxf(m, fabsf(acc[nt][r]));
        m = fmaxf(m, __shfl_xor(m, 1));
        m = fmaxf(m, __shfl_xor(m, 2));
        m = fmaxf(m, __shfl_xor(m, 4));
        m = fmaxf(m, __shfl_xor(m, 8));
        int row = m0 + quad * 4 + r;
        float rs = (m > 0.f) ? 127.f / m : 0.f;
        if (l16 == 0) sc2[row] = (m > 0.f) ? m / 127.f : 0.f;
#pragma unroll
        for (int nt = 0; nt < 4; nt++) {
            int qv = (int)rintf(acc[nt][r] * rs) + 128;
            z2[(long)row * 64 + nt * 16 + l16] = (unsigned char)qv;
        }
    }
}

// ---------------------------------------------------------------------------
// Layer-2 gather+normalize, SUBGROUP-PER-NODE, int8 rows: wave = 8x 8-lane
// subgroups, one node per subgroup (8 lanes x 8B = full 64B int8 z2 row =
// ONE cache line per gather). csr8.x index + per-edge sc2 load (sc2 400KB,
// L2-resident; csr8.y is sc1 -- wrong layer here, must NOT be used).
// ---------------------------------------------------------------------------
__global__ __launch_bounds__(256, 8) void gather64(
    const unsigned char* __restrict__ z, const float* __restrict__ sc,
    const int2* __restrict__ csr8,
    const int* __restrict__ begs, const int* __restrict__ ends,
    const float* __restrict__ bias, float4* __restrict__ out) {
    int tid = threadIdx.x;
    int lane = tid & 63;
    int c = lane & 7;                         // channel block: c*8..c*8+7
    int node = blockIdx.x * 32 + (tid >> 3);  // 3125*32 == NNODES exactly

    int beg = begs[node];
    int end = ends[node];

    unsigned coff = (unsigned)c << 3;

    float a[8];
#pragma unroll
    for (int j = 0; j < 8; j++) a[j] = 0.f;
    float ssum = 0.f;

    {
        float s = sc[node];
        uint2 u = *(const uint2*)(z + (((unsigned)node) << 6) + coff);
        ssum += s;
        acc8(s, u, a);
    }

    int e = beg;
    while (__any(e < end)) {
        float s0 = 0.f, s1 = 0.f, s2 = 0.f, s3 = 0.f;
        float s4 = 0.f, s5 = 0.f, s6 = 0.f, s7 = 0.f;
        uint2 u0 = make_uint2(0, 0), u1 = make_uint2(0, 0);
        uint2 u2 = make_uint2(0, 0), u3 = make_uint2(0, 0);
        uint2 u4 = make_uint2(0, 0), u5 = make_uint2(0, 0);
        uint2 u6 = make_uint2(0, 0), u7 = make_uint2(0, 0);
        if (e     < end) { int i = csr8[e    ].x; s0 = sc[i]; u0 = *(const uint2*)(z + (((unsigned)i) << 6) + coff); }
        if (e + 1 < end) { int i = csr8[e + 1].x; s1 = sc[i]; u1 = *(const uint2*)(z + (((unsigned)i) << 6) + coff); }
        if (e + 2 < end) { int i = csr8[e + 2].x; s2 = sc[i]; u2 = *(const uint2*)(z + (((unsigned)i) << 6) + coff); }
        if (e + 3 < end) { int i = csr8[e + 3].x; s3 = sc[i]; u3 = *(const uint2*)(z + (((unsigned)i) << 6) + coff); }
        if (e + 4 < end) { int i = csr8[e + 4].x; s4 = sc[i]; u4 = *(const uint2*)(z + (((unsigned)i) << 6) + coff); }
        if (e + 5 < end) { int i = csr8[e + 5].x; s5 = sc[i]; u5 = *(const uint2*)(z + (((unsigned)i) << 6) + coff); }
        if (e + 6 < end) { int i = csr8[e + 6].x; s6 = sc[i]; u6 = *(const uint2*)(z + (((unsigned)i) << 6) + coff); }
        if (e + 7 < end) { int i = csr8[e + 7].x; s7 = sc[i]; u7 = *(const uint2*)(z + (((unsigned)i) << 6) + coff); }
        ssum += ((s0 + s1) + (s2 + s3)) + ((s4 + s5) + (s6 + s7));
        acc8(s0, u0, a); acc8(s1, u1, a); acc8(s2, u2, a); acc8(s3, u3, a);
        acc8(s4, u4, a); acc8(s5, u5, a); acc8(s6, u6, a); acc8(s7, u7, a);
        e += 8;
    }

    {
        float base = 128.f * ssum;
        float inv = 1.0f / (float)(end - beg + 1);
        float4 b0 = ((const float4*)bias)[c * 2];
        float4 b1v = ((const float4*)bias)[c * 2 + 1];
        out[(long)node * 16 + c * 2] =
            make_float4((a[0] - base) * inv + b0.x, (a[1] - base) * inv + b0.y,
                        (a[2] - base) * inv + b0.z, (a[3] - base) * inv + b0.w);
        out[(long)node * 16 + c * 2 + 1] =
            make_float4((a[4] - base) * inv + b1v.x, (a[5] - base) * inv + b1v.y,
                        (a[6] - base) * inv + b1v.z, (a[7] - base) * inv + b1v.w);
    }
}

extern "C" void kernel_launch(void* const* d_in, const int* in_sizes, int n_in,
                              void* d_out, int out_size, void* d_ws, size_t ws_size,
                              hipStream_t stream) {
    const float* feat = (const float*)d_in[0];
    const float* W1   = (const float*)d_in[1];
    const float* b1   = (const float*)d_in[2];
    const float* W2   = (const float*)d_in[3];
    const float* b2   = (const float*)d_in[4];
    const int*   src  = (const int*)d_in[5];
    const int*   dst  = (const int*)d_in[6];
    float* out = (float*)d_out;

    // Workspace layout:
    //   bcur i32[782]            @ 0x0000000
    //   begs i32[100000]         @ 0x0001000
    //   ends i32[100000]         @ 0x0063000
    //   ebuf i32[NB*CAP]         @ 0x00C5000  (8.0 MB)
    //   csr8 int2[NB*CAP]        @ 0x0900000  (16.0 MB)
    //   z1   u8 [12.8M]          @ 0x1900000
    //   sc1  f32[100000]         @ 0x2600000
    //   h1   f16[12.8M]          @ 0x2700000  (25.6 MB)
    //   z2   u8 [6.4M]           @ 0x4100000
    //   sc2  f32[100000]         @ 0x4800000
    //   W1t  f16[16384]          @ 0x4900000
    //   W2t  f16[8192]           @ 0x4910000
    char* ws = (char*)d_ws;
    int* bcur = (int*)(ws + 0x0000000);
    int* begs = (int*)(ws + 0x0001000);
    int* ends = (int*)(ws + 0x0063000);
    int* ebuf = (int*)(ws + 0x00C5000);
    int2* csr8 = (int2*)(ws + 0x0900000);
    unsigned char* z1 = (unsigned char*)(ws + 0x1900000);
    float* sc1 = (float*)(ws + 0x2600000);
    f16* h1   = (f16*)(ws + 0x2700000);
    unsigned char* z2 = (unsigned char*)(ws + 0x4100000);
    float* sc2 = (float*)(ws + 0x4800000);
    f16* W1t  = (f16*)(ws + 0x4900000);
    f16* W2t  = (f16*)(ws + 0x4910000);

    // 1. init cursors + weight prep (no memsets needed anywhere)
    init_k<<<100, 256, 0, stream>>>(bcur, W1, W1t, W2, W2t);

    // 2. edge scatter into padded buckets + layer-1 GEMM (fused)
    scatter_gemm1<<<EBLOCKS + GEMM_BLOCKS, 256, 0, stream>>>(src, dst, bcur, ebuf,
                                                             feat, W1t, z1, sc1);

    // 3. per-bucket CSR fill ({src,sc1} csr8) + per-node beg/end
    fill_bucket<<<NB, 256, 0, stream>>>(ebuf, bcur, sc1, begs, ends, csr8);

    // 4. layer-1 gather (+bias+relu) -> h1, barrier-free small blocks
    gather128_h1<<<NNODES / 16, 256, 0, stream>>>(z1, sc1, csr8, begs, ends,
                                                  b1, h1);

    // 5. layer-2 projection: z2 = int8(h1 @ W2t^T) + sc2
    gemm2_k<<<GEMM_BLOCKS, 256, 0, stream>>>(h1, W2t, z2, sc2);

    // 6. layer-2 gather (+bias) -> output; 32 nodes/block, 3125*32 = 100000
    gather64<<<3125, 256, 0, stream>>>(z2, sc2, csr8, begs, ends, b2,
                                       (float4*)out);
}